// Round 1
// baseline (389.831 us; speedup 1.0000x reference)
//
#include <hip/hip_runtime.h>
#include <math.h>

#define SS 7
#define NROIS 64
#define CC 2048
#define DD (SS*SS*CC)   // 100352
#define MM 64
#define NN 1024
#define KCHUNK1 2048
#define KC1 49          // 49*2048 = 100352

// ---------------- Stage 1: crop + bilinear resize (TF2 half-pixel) ----------
// grid: (64 rois, 49 positions), block 512: each thread does one float4 of C.
__global__ void crop_kernel(const float* __restrict__ fm,
                            const float* __restrict__ boxes,
                            float* __restrict__ X) {
    int roi = blockIdx.x;
    int p   = blockIdx.y;         // 0..48
    int sy = p / SS, sx = p % SS;
    const float* b = boxes + roi * 4;
    float x1 = fmaxf(0.f, rintf(b[0]));     // jnp.round = half-to-even = rintf
    float y1 = fmaxf(0.f, rintf(b[1]));
    float x2 = fminf(15.f, rintf(b[2]));
    float y2 = fminf(15.f, rintf(b[3]));
    float h = y2 - y1, w = x2 - x1;
    float iy = ((sy + 0.5f) * h) / 7.0f - 0.5f;
    float ix = ((sx + 0.5f) * w) / 7.0f - 0.5f;
    iy = fminf(fmaxf(iy, 0.f), h - 1.f);
    ix = fminf(fmaxf(ix, 0.f), w - 1.f);
    float y0 = floorf(iy), x0 = floorf(ix);
    float fy = iy - y0,   fx = ix - x0;
    int y0i = (int)(y1 + y0);
    int y1i = min(y0i + 1, (int)(y1 + h - 1.f));
    int x0i = (int)(x1 + x0);
    int x1i = min(x0i + 1, (int)(x1 + w - 1.f));

    int c = threadIdx.x * 4;   // 512 threads * 4 = 2048
    const float4 v00 = *(const float4*)(fm + ((size_t)(y0i*16 + x0i))*CC + c);
    const float4 v01 = *(const float4*)(fm + ((size_t)(y0i*16 + x1i))*CC + c);
    const float4 v10 = *(const float4*)(fm + ((size_t)(y1i*16 + x0i))*CC + c);
    const float4 v11 = *(const float4*)(fm + ((size_t)(y1i*16 + x1i))*CC + c);
    float gy = 1.f - fy, gx = 1.f - fx;
    float4 o;
    o.x = (v00.x*gy + v10.x*fy)*gx + (v01.x*gy + v11.x*fy)*fx;
    o.y = (v00.y*gy + v10.y*fy)*gx + (v01.y*gy + v11.y*fy)*fx;
    o.z = (v00.z*gy + v10.z*fy)*gx + (v01.z*gy + v11.z*fy)*fx;
    o.w = (v00.w*gy + v10.w*fy)*gx + (v01.w*gy + v11.w*fy)*fx;
    *(float4*)(X + (size_t)roi*DD + (size_t)p*CC + c) = o;
}

// ---------------- Stage 2: K-split partial GEMM -----------------------------
// C_partial[kc][64][1024] for cols [nt*128, nt*128+128), k in [kc*kchunk, ...)
// block 256 = (tx 0..15, ty 0..15); thread computes rows ty*4..+3,
// cols c0 + {tx*4+0..3, 64+tx*4+0..3}.
__global__ __launch_bounds__(256)
void gemm_partial(const float* __restrict__ X, const float* __restrict__ Wm,
                  float* __restrict__ P, int K, int kchunk) {
    int nt = blockIdx.x, kc = blockIdx.y;
    int c0 = nt * 128;
    int k0 = kc * kchunk;
    int t = threadIdx.x, tx = t & 15, ty = t >> 4;

    __shared__ float wsh[32][128];
    __shared__ float xsh[64][33];   // +1 pad

    float acc[4][8];
    #pragma unroll
    for (int i = 0; i < 4; ++i)
        #pragma unroll
        for (int j = 0; j < 8; ++j) acc[i][j] = 0.f;

    for (int kt = 0; kt < kchunk; kt += 32) {
        // stage W tile [32][128]
        #pragma unroll
        for (int i = 0; i < 4; ++i) {
            int lin = t + i * 256;
            int kk = lin >> 5, cc = (lin & 31) * 4;
            float4 v = *(const float4*)(Wm + (size_t)(k0 + kt + kk) * NN + c0 + cc);
            *(float4*)&wsh[kk][cc] = v;
        }
        // stage X tile [64][32]
        #pragma unroll
        for (int i = 0; i < 2; ++i) {
            int lin = t + i * 256;
            int m = lin >> 3, kk = (lin & 7) * 4;
            float4 v = *(const float4*)(X + (size_t)m * K + k0 + kt + kk);
            xsh[m][kk+0] = v.x; xsh[m][kk+1] = v.y;
            xsh[m][kk+2] = v.z; xsh[m][kk+3] = v.w;
        }
        __syncthreads();
        #pragma unroll
        for (int kk = 0; kk < 32; ++kk) {
            float wv[8];
            *(float4*)&wv[0] = *(const float4*)&wsh[kk][tx*4];
            *(float4*)&wv[4] = *(const float4*)&wsh[kk][64 + tx*4];
            float xr[4];
            #pragma unroll
            for (int i = 0; i < 4; ++i) xr[i] = xsh[ty*4 + i][kk];
            #pragma unroll
            for (int i = 0; i < 4; ++i)
                #pragma unroll
                for (int j = 0; j < 8; ++j)
                    acc[i][j] += xr[i] * wv[j];
        }
        __syncthreads();
    }
    // write partials
    #pragma unroll
    for (int i = 0; i < 4; ++i) {
        int m = ty*4 + i;
        float4 va = {acc[i][0], acc[i][1], acc[i][2], acc[i][3]};
        float4 vb = {acc[i][4], acc[i][5], acc[i][6], acc[i][7]};
        *(float4*)(P + ((size_t)kc*MM + m) * NN + c0 + tx*4)      = va;
        *(float4*)(P + ((size_t)kc*MM + m) * NN + c0 + 64 + tx*4) = vb;
    }
}

// ---------------- Stage 3: reduce partials + bias + relu --------------------
__global__ void reduce_bias_relu(const float* __restrict__ P,
                                 const float* __restrict__ bias,
                                 float* __restrict__ Y, int KC) {
    int idx = blockIdx.x * 256 + threadIdx.x;   // 0..65535
    int n = idx & (NN - 1);
    float s = bias[n];
    for (int kc = 0; kc < KC; ++kc) s += P[(size_t)kc * (MM*NN) + idx];
    Y[idx] = fmaxf(s, 0.f);
}

// ---------------- Stage 4: heads (cls softmax + bbox) -----------------------
__global__ void heads_kernel(const float* __restrict__ h2,
                             const float* __restrict__ Wc, const float* __restrict__ bc,
                             const float* __restrict__ Wb, const float* __restrict__ bb,
                             float* __restrict__ out) {
    int m = blockIdx.x;
    int t = threadIdx.x;   // 256
    float a[6] = {0,0,0,0,0,0};
    for (int k = t; k < 1024; k += 256) {
        float xv = h2[(size_t)m * 1024 + k];
        a[0] += xv * Wc[k*2 + 0];
        a[1] += xv * Wc[k*2 + 1];
        a[2] += xv * Wb[k*4 + 0];
        a[3] += xv * Wb[k*4 + 1];
        a[4] += xv * Wb[k*4 + 2];
        a[5] += xv * Wb[k*4 + 3];
    }
    __shared__ float red[6][256];
    #pragma unroll
    for (int j = 0; j < 6; ++j) red[j][t] = a[j];
    __syncthreads();
    for (int s = 128; s > 0; s >>= 1) {
        if (t < s) {
            #pragma unroll
            for (int j = 0; j < 6; ++j) red[j][t] += red[j][t + s];
        }
        __syncthreads();
    }
    if (t == 0) {
        float l0 = red[0][0] + bc[0], l1 = red[1][0] + bc[1];
        float mx = fmaxf(l0, l1);
        float e0 = expf(l0 - mx), e1 = expf(l1 - mx);
        float inv = 1.f / (e0 + e1);
        out[m*2 + 0] = e0 * inv;
        out[m*2 + 1] = e1 * inv;
        out[128 + m*4 + 0] = red[2][0] + bb[0];
        out[128 + m*4 + 1] = red[3][0] + bb[1];
        out[128 + m*4 + 2] = red[4][0] + bb[2];
        out[128 + m*4 + 3] = red[5][0] + bb[3];
    }
}

extern "C" void kernel_launch(void* const* d_in, const int* in_sizes, int n_in,
                              void* d_out, int out_size, void* d_ws, size_t ws_size,
                              hipStream_t stream) {
    const float* fm    = (const float*)d_in[0];
    const float* boxes = (const float*)d_in[1];
    const float* W1    = (const float*)d_in[2];
    const float* b1    = (const float*)d_in[3];
    const float* W2    = (const float*)d_in[4];
    const float* b2    = (const float*)d_in[5];
    const float* Wc    = (const float*)d_in[6];
    const float* bc    = (const float*)d_in[7];
    const float* Wb    = (const float*)d_in[8];
    const float* bb    = (const float*)d_in[9];
    float* out = (float*)d_out;
    float* ws  = (float*)d_ws;

    float* X  = ws;                          // 64*100352      = 6,422,528 f
    float* P1 = X  + (size_t)NROIS * DD;     // 49*64*1024     = 3,211,264 f
    float* h1 = P1 + (size_t)KC1 * MM * NN;  // 65,536 f
    float* P2 = h1 + (size_t)MM * NN;        // 65,536 f
    float* h2 = P2 + (size_t)MM * NN;        // 65,536 f
    // total ~9.8M floats = ~39.3 MB of d_ws

    crop_kernel<<<dim3(NROIS, SS*SS), 512, 0, stream>>>(fm, boxes, X);
    gemm_partial<<<dim3(8, KC1), 256, 0, stream>>>(X, W1, P1, DD, KCHUNK1);
    reduce_bias_relu<<<(MM*NN)/256, 256, 0, stream>>>(P1, b1, h1, KC1);
    gemm_partial<<<dim3(8, 1), 256, 0, stream>>>(h1, W2, P2, NN, NN);
    reduce_bias_relu<<<(MM*NN)/256, 256, 0, stream>>>(P2, b2, h2, 1);
    heads_kernel<<<NROIS, 256, 0, stream>>>(h2, Wc, bc, Wb, bb, out);
}

// Round 2
// 244.200 us; speedup vs baseline: 1.5964x; 1.5964x over previous
//
#include <hip/hip_runtime.h>
#include <math.h>

#define SS 7
#define NROIS 64
#define CC 2048
#define DD (SS*SS*CC)   // 100352
#define MM 64
#define NN 1024
#define KCH 2048
#define KC1 49          // 49*2048 = 100352

typedef float f32x4 __attribute__((ext_vector_type(4)));
typedef __bf16 bf16x8 __attribute__((ext_vector_type(8)));
typedef unsigned int uintx4 __attribute__((ext_vector_type(4)));

__device__ __forceinline__ unsigned short f2bf(float f){
    unsigned u = __builtin_bit_cast(unsigned, f);
    u += 0x7fffu + ((u >> 16) & 1u);           // round-to-nearest-even
    return (unsigned short)(u >> 16);
}
__device__ __forceinline__ float bf2f(unsigned short h){
    unsigned u = ((unsigned)h) << 16;
    return __builtin_bit_cast(float, u);
}

// ---------------- Stage 1: crop + bilinear resize -> bf16 hi/lo planes ------
__global__ void crop_kernel(const float* __restrict__ fm,
                            const float* __restrict__ boxes,
                            unsigned short* __restrict__ Xhi,
                            unsigned short* __restrict__ Xlo) {
    int roi = blockIdx.x;
    int p   = blockIdx.y;         // 0..48
    int sy = p / SS, sx = p % SS;
    const float* b = boxes + roi * 4;
    float x1 = fmaxf(0.f, rintf(b[0]));
    float y1 = fmaxf(0.f, rintf(b[1]));
    float x2 = fminf(15.f, rintf(b[2]));
    float y2 = fminf(15.f, rintf(b[3]));
    float h = y2 - y1, w = x2 - x1;
    float iy = ((sy + 0.5f) * h) / 7.0f - 0.5f;
    float ix = ((sx + 0.5f) * w) / 7.0f - 0.5f;
    iy = fminf(fmaxf(iy, 0.f), h - 1.f);
    ix = fminf(fmaxf(ix, 0.f), w - 1.f);
    float y0 = floorf(iy), x0 = floorf(ix);
    float fy = iy - y0,   fx = ix - x0;
    int y0i = (int)(y1 + y0);
    int y1i = min(y0i + 1, (int)(y1 + h - 1.f));
    int x0i = (int)(x1 + x0);
    int x1i = min(x0i + 1, (int)(x1 + w - 1.f));

    int c = threadIdx.x * 4;
    const float4 v00 = *(const float4*)(fm + ((size_t)(y0i*16 + x0i))*CC + c);
    const float4 v01 = *(const float4*)(fm + ((size_t)(y0i*16 + x1i))*CC + c);
    const float4 v10 = *(const float4*)(fm + ((size_t)(y1i*16 + x0i))*CC + c);
    const float4 v11 = *(const float4*)(fm + ((size_t)(y1i*16 + x1i))*CC + c);
    float gy = 1.f - fy, gx = 1.f - fx;
    float o[4];
    o[0] = (v00.x*gy + v10.x*fy)*gx + (v01.x*gy + v11.x*fy)*fx;
    o[1] = (v00.y*gy + v10.y*fy)*gx + (v01.y*gy + v11.y*fy)*fx;
    o[2] = (v00.z*gy + v10.z*fy)*gx + (v01.z*gy + v11.z*fy)*fx;
    o[3] = (v00.w*gy + v10.w*fy)*gx + (v01.w*gy + v11.w*fy)*fx;
    unsigned short hh[4], ll[4];
    #pragma unroll
    for (int j = 0; j < 4; ++j) {
        hh[j] = f2bf(o[j]);
        ll[j] = f2bf(o[j] - bf2f(hh[j]));
    }
    size_t off = (size_t)roi*DD + (size_t)p*CC + c;
    uint2 hv, lv;
    hv.x = (unsigned)hh[0] | ((unsigned)hh[1] << 16);
    hv.y = (unsigned)hh[2] | ((unsigned)hh[3] << 16);
    lv.x = (unsigned)ll[0] | ((unsigned)ll[1] << 16);
    lv.y = (unsigned)ll[2] | ((unsigned)ll[3] << 16);
    *(uint2*)(Xhi + off) = hv;
    *(uint2*)(Xlo + off) = lv;
}

// ---------------- Stage 2: FC1 via bf16x2-split MFMA ------------------------
// grid (16 n-tiles of 64, 49 k-chunks of 2048), 256 thr = 4 waves.
// Wave tile 64m x 16n: 4 m-frags x 1 n-frag of mfma_f32_16x16x32_bf16.
// 3-term split: D += Ahi*Bhi + Ahi*Blo + Alo*Bhi  (fp32-grade accuracy).
__global__ __launch_bounds__(256)
void fc1_mfma(const unsigned short* __restrict__ Xhi,
              const unsigned short* __restrict__ Xlo,
              const float* __restrict__ W1, float* __restrict__ P) {
    const int nb = blockIdx.x, kc = blockIdx.y;
    const int n0 = nb * 64;
    const int k0 = kc * KCH;
    const int t = threadIdx.x;
    const int lane = t & 63, wv = t >> 6;
    const int kp = t & 15, no = t >> 4;      // W staging: k-pair, n-quad
    const int xr = t >> 2, xc = t & 3;       // X staging: row, col-quarter

    __shared__ unsigned short WTh[64][72];   // [n][k] transposed, hi
    __shared__ unsigned short WTl[64][72];   // lo
    __shared__ unsigned short XSh[64][72];   // [m][k] hi
    __shared__ unsigned short XSl[64][72];   // lo

    f32x4 acc[4];
    #pragma unroll
    for (int i = 0; i < 4; ++i) acc[i] = (f32x4){0.f, 0.f, 0.f, 0.f};

    float4 wr0, wr1, wr2, wr3;
    uintx4 xh0, xh1, xl0, xl1;

    const float* wbase = W1 + (size_t)k0 * NN + n0 + no * 4;
    const unsigned short* xhb = Xhi + (size_t)xr * DD + k0 + xc * 16;
    const unsigned short* xlb = Xlo + (size_t)xr * DD + k0 + xc * 16;

    // prefetch kt = 0
    {
        const float* p = wbase + (size_t)(2 * kp) * NN;
        wr0 = *(const float4*)(p);
        wr1 = *(const float4*)(p + NN);
        wr2 = *(const float4*)(p + 32 * NN);
        wr3 = *(const float4*)(p + 33 * NN);
        xh0 = *(const uintx4*)(xhb); xh1 = *(const uintx4*)(xhb + 8);
        xl0 = *(const uintx4*)(xlb); xl1 = *(const uintx4*)(xlb + 8);
    }

    for (int kt = 0; kt < KCH / 64; ++kt) {
        __syncthreads();
        // ---- stage current tile into LDS (fp32 -> bf16 hi/lo, W transposed)
        {
            const float* a0 = (const float*)&wr0;   // k = 2kp
            const float* a1 = (const float*)&wr1;   // k = 2kp+1
            const float* a2 = (const float*)&wr2;   // k = 2kp+32
            const float* a3 = (const float*)&wr3;   // k = 2kp+33
            #pragma unroll
            for (int j = 0; j < 4; ++j) {
                int n = no * 4 + j;
                {
                    float v0 = a0[j], v1 = a1[j];
                    unsigned short h0 = f2bf(v0), h1 = f2bf(v1);
                    unsigned short l0 = f2bf(v0 - bf2f(h0));
                    unsigned short l1 = f2bf(v1 - bf2f(h1));
                    *(unsigned*)&WTh[n][2*kp] = (unsigned)h0 | ((unsigned)h1 << 16);
                    *(unsigned*)&WTl[n][2*kp] = (unsigned)l0 | ((unsigned)l1 << 16);
                }
                {
                    float v0 = a2[j], v1 = a3[j];
                    unsigned short h0 = f2bf(v0), h1 = f2bf(v1);
                    unsigned short l0 = f2bf(v0 - bf2f(h0));
                    unsigned short l1 = f2bf(v1 - bf2f(h1));
                    *(unsigned*)&WTh[n][2*kp + 32] = (unsigned)h0 | ((unsigned)h1 << 16);
                    *(unsigned*)&WTl[n][2*kp + 32] = (unsigned)l0 | ((unsigned)l1 << 16);
                }
            }
            *(uintx4*)&XSh[xr][xc*16]     = xh0;
            *(uintx4*)&XSh[xr][xc*16 + 8] = xh1;
            *(uintx4*)&XSl[xr][xc*16]     = xl0;
            *(uintx4*)&XSl[xr][xc*16 + 8] = xl1;
        }
        // ---- prefetch next tile (stays in flight across the MFMA phase)
        if (kt + 1 < KCH / 64) {
            const float* p = wbase + (size_t)((kt + 1) * 64 + 2 * kp) * NN;
            wr0 = *(const float4*)(p);
            wr1 = *(const float4*)(p + NN);
            wr2 = *(const float4*)(p + 32 * NN);
            wr3 = *(const float4*)(p + 33 * NN);
            const unsigned short* ph = xhb + (kt + 1) * 64;
            const unsigned short* pl = xlb + (kt + 1) * 64;
            xh0 = *(const uintx4*)ph; xh1 = *(const uintx4*)(ph + 8);
            xl0 = *(const uintx4*)pl; xl1 = *(const uintx4*)(pl + 8);
        }
        __syncthreads();
        // ---- MFMA phase: 2 k-steps of 32
        #pragma unroll
        for (int ks = 0; ks < 2; ++ks) {
            const int kk = ks * 32 + (lane >> 4) * 8;
            bf16x8 Bh = *(const bf16x8*)&WTh[wv*16 + (lane & 15)][kk];
            bf16x8 Bl = *(const bf16x8*)&WTl[wv*16 + (lane & 15)][kk];
            #pragma unroll
            for (int mf = 0; mf < 4; ++mf) {
                bf16x8 Ah = *(const bf16x8*)&XSh[mf*16 + (lane & 15)][kk];
                bf16x8 Al = *(const bf16x8*)&XSl[mf*16 + (lane & 15)][kk];
                acc[mf] = __builtin_amdgcn_mfma_f32_16x16x32_bf16(Ah, Bh, acc[mf], 0, 0, 0);
                acc[mf] = __builtin_amdgcn_mfma_f32_16x16x32_bf16(Ah, Bl, acc[mf], 0, 0, 0);
                acc[mf] = __builtin_amdgcn_mfma_f32_16x16x32_bf16(Al, Bh, acc[mf], 0, 0, 0);
            }
        }
    }
    // ---- write partials: D row = (lane>>4)*4 + i, col = lane&15
    const int oc  = n0 + wv * 16 + (lane & 15);
    const int orb = (lane >> 4) * 4;
    #pragma unroll
    for (int mf = 0; mf < 4; ++mf)
        #pragma unroll
        for (int i = 0; i < 4; ++i) {
            int m = mf * 16 + orb + i;
            P[((size_t)kc * MM + m) * NN + oc] = acc[mf][i];
        }
}

// ---------------- Stage 3: reduce partials + bias + relu --------------------
__global__ void reduce_bias_relu(const float* __restrict__ P,
                                 const float* __restrict__ bias,
                                 float* __restrict__ Y, int KC) {
    int idx = blockIdx.x * 256 + threadIdx.x;   // 0..65535
    int n = idx & (NN - 1);
    float s = bias[n];
    for (int kc = 0; kc < KC; ++kc) s += P[(size_t)kc * (MM*NN) + idx];
    Y[idx] = fmaxf(s, 0.f);
}

// ---------------- Stage 4: FC2 fused bias+relu (fp32, partial-free) ---------
// grid (16 n-tiles of 64, 4 m-tiles of 16), 256 thr.
__global__ __launch_bounds__(256)
void fc2_relu(const float* __restrict__ h1, const float* __restrict__ W2,
              const float* __restrict__ b2, float* __restrict__ h2) {
    int nb = blockIdx.x, mb = blockIdx.y;
    int t = threadIdx.x;
    __shared__ float xs[16][1024];
    #pragma unroll
    for (int i = 0; i < 16; ++i) {
        int idx = t + i * 256;      // float4 index 0..4095
        *(float4*)&xs[idx >> 8][(idx & 255) * 4] =
            *(const float4*)(h1 + (size_t)(mb*16 + (idx >> 8)) * NN + (idx & 255) * 4);
    }
    __syncthreads();
    int n  = nb * 64 + (t & 63);
    int mg = (t >> 6) * 4;
    float a[4] = {0.f, 0.f, 0.f, 0.f};
    for (int k = 0; k < 1024; ++k) {
        float wvv = W2[(size_t)k * NN + n];
        #pragma unroll
        for (int i = 0; i < 4; ++i) a[i] += xs[mg + i][k] * wvv;
    }
    float bias = b2[n];
    #pragma unroll
    for (int i = 0; i < 4; ++i)
        h2[(size_t)(mb*16 + mg + i) * NN + n] = fmaxf(a[i] + bias, 0.f);
}

// ---------------- Stage 5: heads --------------------------------------------
__global__ void heads_kernel(const float* __restrict__ h2,
                             const float* __restrict__ Wc, const float* __restrict__ bc,
                             const float* __restrict__ Wb, const float* __restrict__ bb,
                             float* __restrict__ out) {
    int m = blockIdx.x;
    int t = threadIdx.x;   // 256
    float a[6] = {0,0,0,0,0,0};
    for (int k = t; k < 1024; k += 256) {
        float xv = h2[(size_t)m * 1024 + k];
        a[0] += xv * Wc[k*2 + 0];
        a[1] += xv * Wc[k*2 + 1];
        a[2] += xv * Wb[k*4 + 0];
        a[3] += xv * Wb[k*4 + 1];
        a[4] += xv * Wb[k*4 + 2];
        a[5] += xv * Wb[k*4 + 3];
    }
    __shared__ float red[6][256];
    #pragma unroll
    for (int j = 0; j < 6; ++j) red[j][t] = a[j];
    __syncthreads();
    for (int s = 128; s > 0; s >>= 1) {
        if (t < s) {
            #pragma unroll
            for (int j = 0; j < 6; ++j) red[j][t] += red[j][t + s];
        }
        __syncthreads();
    }
    if (t == 0) {
        float l0 = red[0][0] + bc[0], l1 = red[1][0] + bc[1];
        float mx = fmaxf(l0, l1);
        float e0 = expf(l0 - mx), e1 = expf(l1 - mx);
        float inv = 1.f / (e0 + e1);
        out[m*2 + 0] = e0 * inv;
        out[m*2 + 1] = e1 * inv;
        out[128 + m*4 + 0] = red[2][0] + bb[0];
        out[128 + m*4 + 1] = red[3][0] + bb[1];
        out[128 + m*4 + 2] = red[4][0] + bb[2];
        out[128 + m*4 + 3] = red[5][0] + bb[3];
    }
}

extern "C" void kernel_launch(void* const* d_in, const int* in_sizes, int n_in,
                              void* d_out, int out_size, void* d_ws, size_t ws_size,
                              hipStream_t stream) {
    const float* fm    = (const float*)d_in[0];
    const float* boxes = (const float*)d_in[1];
    const float* W1    = (const float*)d_in[2];
    const float* b1    = (const float*)d_in[3];
    const float* W2    = (const float*)d_in[4];
    const float* b2    = (const float*)d_in[5];
    const float* Wc    = (const float*)d_in[6];
    const float* bc    = (const float*)d_in[7];
    const float* Wb    = (const float*)d_in[8];
    const float* bb    = (const float*)d_in[9];
    float* out = (float*)d_out;
    char* ws = (char*)d_ws;

    const size_t XB = (size_t)NROIS * DD * sizeof(unsigned short);  // 12,845,056
    unsigned short* Xhi = (unsigned short*)ws;
    unsigned short* Xlo = (unsigned short*)(ws + XB);
    float* P1 = (float*)(ws + 2 * XB);                 // 49*64*1024*4 = 12,845,056
    float* h1 = (float*)(ws + 3 * XB);                 // 262,144
    float* h2 = (float*)(ws + 3 * XB + (size_t)MM * NN * sizeof(float));
    // total ws use: 3*12,845,056 + 2*262,144 = 39,059,456 B

    crop_kernel<<<dim3(NROIS, SS*SS), 512, 0, stream>>>(fm, boxes, Xhi, Xlo);
    fc1_mfma<<<dim3(16, KC1), 256, 0, stream>>>(Xhi, Xlo, W1, P1);
    reduce_bias_relu<<<(MM*NN)/256, 256, 0, stream>>>(P1, b1, h1, KC1);
    fc2_relu<<<dim3(16, 4), 256, 0, stream>>>(h1, W2, b2, h2);
    heads_kernel<<<NROIS, 256, 0, stream>>>(h2, Wc, bc, Wb, bb, out);
}